// Round 10
// baseline (695.823 us; speedup 1.0000x reference)
//
#include <hip/hip_runtime.h>
#include <hip/hip_fp16.h>

#define N_NODES 20000
#define N_EDGES 320000
#define DIM 256
// H=8 heads, C=32 channels/head

typedef _Float16 f16;
typedef unsigned int u32;
typedef f16 f16x8 __attribute__((ext_vector_type(8)));
typedef f16 f16x4 __attribute__((ext_vector_type(4)));
typedef float f32x4 __attribute__((ext_vector_type(4)));

#define GLL16(gsrc, ldst) __builtin_amdgcn_global_load_lds( \
    (const u32 __attribute__((address_space(1)))*)(gsrc),   \
    (u32 __attribute__((address_space(3)))*)(ldst), 16, 0, 0)

// ---- prep: weights f32 (K x N) -> f16 transposed (N x K); We f16 row-major;
//      pack biases; zero deg ----
__global__ void prep_all(const float* __restrict__ Wq, const float* __restrict__ Wk,
                         const float* __restrict__ Wv, const float* __restrict__ Ws,
                         const float* __restrict__ We,
                         const float* __restrict__ bq, const float* __restrict__ bk,
                         const float* __restrict__ bv, const float* __restrict__ bs,
                         f16* __restrict__ wtbase, f16* __restrict__ wef16,
                         float* __restrict__ biasAll, int* __restrict__ deg) {
    if (blockIdx.x < 1280) {
        int gid = blockIdx.x * 256 + threadIdx.x;
        int w = gid >> 16;            // 0..4 : q,k,v,s,e
        int idx = gid & 65535;
        int k = idx >> 8, n = idx & 255;
        const float* W = (w == 0) ? Wq : (w == 1) ? Wk : (w == 2) ? Wv : (w == 3) ? Ws : We;
        wtbase[w * 65536 + n * 256 + k] = (f16)W[k * 256 + n];
    } else if (blockIdx.x < 1536) {
        int idx = (blockIdx.x - 1280) * 256 + threadIdx.x;  // 0..65535
        wef16[idx] = (f16)We[idx];                          // row-major [d][hc]
    } else if (blockIdx.x < 1540) {
        int i = (blockIdx.x - 1536) * 256 + threadIdx.x;    // 0..1023
        int y = i >> 8, col = i & 255;
        const float* b = (y == 0) ? bq : (y == 1) ? bk : (y == 2) ? bv : bs;
        biasAll[i] = b[col];
    } else {
        int i = (blockIdx.x - 1540) * 256 + threadIdx.x;
        if (i < N_NODES) deg[i] = 0;
    }
}

// ---- node GEMM (R4-proven): q,k,v (f16) + skip (f32), grid (157, 8) ----
__global__ __launch_bounds__(512, 4) void gemm_qkvs(
    const float* __restrict__ A, const f16* __restrict__ WTbase,
    const float* __restrict__ biasAll,
    f16* __restrict__ outF16, float* __restrict__ outF32)
{
    __shared__ __align__(16) char lds[65536];
    const int tid = threadIdx.x;
    const int wave = tid >> 6, lane = tid & 63;
    const int l16 = lane & 15, lg = lane >> 4;
    const int y = blockIdx.y;
    const int outSel = y >> 1, colHalf = y & 1;
    const f16* __restrict__ WT = WTbase + outSel * 65536 + colHalf * 128 * 256;
    const int rowBase = blockIdx.x * 128 + wave * 16;

    const int slot = rowBase + l16;
    const int arow = (slot < N_NODES) ? slot : N_NODES - 1;
    const float* ap = A + (size_t)arow * DIM;
    f32x4 lo[8], hi[8];
#pragma unroll
    for (int ks = 0; ks < 8; ++ks) {
        lo[ks] = *(const f32x4*)(ap + ks * 32 + lg * 8);
        hi[ks] = *(const f32x4*)(ap + ks * 32 + lg * 8 + 4);
    }
    {
        const int p = lane & 31;
#pragma unroll
        for (int r = 0; r < 8; ++r) {
            const int nrel = wave * 16 + r * 2 + (lane >> 5);
            const f16* src = WT + nrel * 256 + (p ^ (nrel & 31)) * 8;
            GLL16(src, &lds[(wave * 16 + r * 2) * 512]);
        }
    }
    f16x8 afr[8];
#pragma unroll
    for (int ks = 0; ks < 8; ++ks) {
#pragma unroll
        for (int j = 0; j < 4; ++j) {
            afr[ks][j]     = (f16)lo[ks][j];
            afr[ks][4 + j] = (f16)hi[ks][j];
        }
    }
    f32x4 acc[8];
#pragma unroll
    for (int c = 0; c < 8; ++c) acc[c] = (f32x4){0.f, 0.f, 0.f, 0.f};

    __syncthreads();

#pragma unroll
    for (int ks = 0; ks < 8; ++ks) {
#pragma unroll
        for (int ct = 0; ct < 8; ++ct) {
            const int nrel = ct * 16 + l16;
            f16x8 b = *(const f16x8*)(lds + nrel * 512 + (((ks * 4 + lg) ^ (nrel & 31)) * 16));
            acc[ct] = __builtin_amdgcn_mfma_f32_16x16x32_f16(afr[ks], b, acc[ct], 0, 0, 0);
        }
    }
#pragma unroll
    for (int ct = 0; ct < 8; ++ct) {
        const int col = colHalf * 128 + ct * 16 + l16;
        const float bv = biasAll[outSel * 256 + col];
#pragma unroll
        for (int i = 0; i < 4; ++i) {
            const int row = rowBase + lg * 4 + i;
            if (row < N_NODES) {
                const float val = acc[ct][i] + bv;
                if (outSel < 3)
                    (outF16 + (size_t)outSel * N_NODES * 256)[(size_t)row * 256 + col] = (f16)val;
                else
                    outF32[(size_t)row * 256 + col] = val;
            }
        }
    }
}

// ---- G GEMM: G[i,h,d] = sum_c We[d, h*32+c] * q[i, h*32+c]  (f16 out) ----
__global__ __launch_bounds__(256, 4) void gemm_g(
    const f16* __restrict__ qf, const f16* __restrict__ wef16, f16* __restrict__ G)
{
    const int tid = threadIdx.x;
    const int wave = tid >> 6, lane = tid & 63;
    const int l16 = lane & 15, lg = lane >> 4;
    const int h = blockIdx.y;
    const int rowBase = blockIdx.x * 64 + wave * 16;

    int arow = rowBase + l16;
    if (arow >= N_NODES) arow = N_NODES - 1;
    f16x8 a = *(const f16x8*)(qf + (size_t)arow * 256 + h * 32 + lg * 8);

    f32x4 acc[16];
#pragma unroll
    for (int c = 0; c < 16; ++c) acc[c] = (f32x4){0.f, 0.f, 0.f, 0.f};
#pragma unroll
    for (int ct = 0; ct < 16; ++ct) {
        f16x8 b = *(const f16x8*)(wef16 + (size_t)(ct * 16 + l16) * 256 + h * 32 + lg * 8);
        acc[ct] = __builtin_amdgcn_mfma_f32_16x16x32_f16(a, b, acc[ct], 0, 0, 0);
    }
#pragma unroll
    for (int ct = 0; ct < 16; ++ct) {
        const int d = ct * 16 + l16;
#pragma unroll
        for (int i = 0; i < 4; ++i) {
            const int row = rowBase + lg * 4 + i;
            if (row < N_NODES)
                G[(size_t)row * 2048 + h * 256 + d] = (f16)acc[ct][i];
        }
    }
}

// ---- CSR build (by dst) ----
__global__ void count_deg(const int* __restrict__ dst, int* __restrict__ deg) {
    int e = blockIdx.x * blockDim.x + threadIdx.x;
    if (e < N_EDGES) atomicAdd(&deg[dst[e]], 1);
}

__global__ __launch_bounds__(1024) void scan_deg(const int* __restrict__ deg,
                                                 int* __restrict__ rowptr,
                                                 int* __restrict__ cursor) {
    __shared__ int part[1024];
    const int t = threadIdx.x;
    const int CH = (N_NODES + 1023) / 1024; // 20
    const int base = t * CH;
    int s = 0;
    for (int i = 0; i < CH; ++i) { int n = base + i; if (n < N_NODES) s += deg[n]; }
    part[t] = s;
    __syncthreads();
    for (int off = 1; off < 1024; off <<= 1) {
        int v = (t >= off) ? part[t - off] : 0;
        __syncthreads();
        part[t] += v;
        __syncthreads();
    }
    int run = (t == 0) ? 0 : part[t - 1];
    for (int i = 0; i < CH; ++i) {
        int n = base + i;
        if (n < N_NODES) { int dn = deg[n]; rowptr[n] = run; cursor[n] = run; run += dn; }
    }
    if (t == 1023) rowptr[N_NODES] = part[1023]; // == E
}

__global__ void scatter_edges(const int* __restrict__ src, const int* __restrict__ dst,
                              int* __restrict__ cursor, int2* __restrict__ es) {
    int e = blockIdx.x * blockDim.x + threadIdx.x;
    if (e < N_EDGES) {
        int p = atomicAdd(&cursor[dst[e]], 1);
        es[p] = make_int2(e, src[e]);   // CSR slot -> (edge id, source node)
    }
}

// ---- fused attention aggregate v4: one wave per node, 2-stage SW pipeline ----
// lane l: head h=l>>3, sublane j=l&7; owns q/k/v channels c0=l*4 and d-slices
// {m*32+j*4} of the 256-d attr space. Two named register contexts A/B hold two
// edges in flight: steady state {COMPUTE A(i); ISSUE A(i+2); COMPUTE B(i+1);
// ISSUE B(i+3)} gives each gather ~2 edge-computes of cover (rule #20: all
// register sets statically named, no runtime-indexed arrays).
// End: out += va/den; G[node][h][:] overwritten with zhat = z/den (f16).
__global__ __launch_bounds__(256, 3) void aggregate4(
    const f16* __restrict__ qf, const f16* __restrict__ kf, const f16* __restrict__ vf,
    f16* __restrict__ G, const float* __restrict__ ea,
    const int2* __restrict__ es, const int* __restrict__ rowptr,
    float* __restrict__ out)
{
    const int wave = threadIdx.x >> 6;
    const int lane = threadIdx.x & 63;
    const int node = blockIdx.x * 4 + wave;
    if (node >= N_NODES) return;
    const int h = lane >> 3, j = lane & 7;
    const int c0 = lane * 4;

    f32x4 qv;
    {
        f16x4 qh = *(const f16x4*)(qf + (size_t)node * 256 + c0);
        qv = (f32x4){(float)qh[0], (float)qh[1], (float)qh[2], (float)qh[3]};
    }
    f32x4 ga[8];
#pragma unroll
    for (int m = 0; m < 8; ++m) {
        f16x4 gh = *(const f16x4*)(G + (size_t)node * 2048 + h * 256 + m * 32 + j * 4);
        ga[m] = (f32x4){(float)gh[0], (float)gh[1], (float)gh[2], (float)gh[3]};
    }

    f32x4 z[8];
#pragma unroll
    for (int m = 0; m < 8; ++m) z[m] = (f32x4){0.f, 0.f, 0.f, 0.f};
    f32x4 va = (f32x4){0.f, 0.f, 0.f, 0.f};
    float den = 0.f;
    const int beg = rowptr[node], end = rowptr[node + 1];
    const int n = end - beg;

    f32x4 eA[8], eB[8];
    f16x4 kA, vA, kB, vB;

#define ISSUE(E_, K_, V_, slot_) do {                                          \
        const int2 _es = es[slot_];                                            \
        const float* _ep = ea + (size_t)_es.x * 256 + j * 4;                   \
        _Pragma("unroll")                                                      \
        for (int _m = 0; _m < 8; ++_m) E_[_m] = *(const f32x4*)(_ep + _m * 32);\
        K_ = *(const f16x4*)(kf + (size_t)_es.y * 256 + c0);                   \
        V_ = *(const f16x4*)(vf + (size_t)_es.y * 256 + c0);                   \
    } while (0)

#define COMPUTE(E_, K_, V_) do {                                               \
        float _dm[8];                                                          \
        _Pragma("unroll")                                                      \
        for (int _m = 0; _m < 8; ++_m)                                         \
            _dm[_m] = E_[_m][0]*ga[_m][0] + E_[_m][1]*ga[_m][1]                \
                    + E_[_m][2]*ga[_m][2] + E_[_m][3]*ga[_m][3];               \
        float _p = ((_dm[0]+_dm[1]) + (_dm[2]+_dm[3]))                         \
                 + ((_dm[4]+_dm[5]) + (_dm[6]+_dm[7]));                        \
        _p += qv[0]*(float)K_[0] + qv[1]*(float)K_[1]                          \
            + qv[2]*(float)K_[2] + qv[3]*(float)K_[3];                         \
        _p += __shfl_xor(_p, 1);                                               \
        _p += __shfl_xor(_p, 2);                                               \
        _p += __shfl_xor(_p, 4);                                               \
        const float _al = __expf(_p * 0.1767766952966369f);                    \
        den += _al;                                                            \
        va[0] += _al * (float)V_[0]; va[1] += _al * (float)V_[1];              \
        va[2] += _al * (float)V_[2]; va[3] += _al * (float)V_[3];              \
        _Pragma("unroll")                                                      \
        for (int _m = 0; _m < 8; ++_m) {                                       \
            z[_m][0] += _al * E_[_m][0]; z[_m][1] += _al * E_[_m][1];          \
            z[_m][2] += _al * E_[_m][2]; z[_m][3] += _al * E_[_m][3];          \
        }                                                                      \
    } while (0)

    if (n >= 2) {
        ISSUE(eA, kA, vA, beg);
        ISSUE(eB, kB, vB, beg + 1);
        int i = beg;
        for (; i + 3 < end; i += 2) {
            COMPUTE(eA, kA, vA); ISSUE(eA, kA, vA, i + 2);
            COMPUTE(eB, kB, vB); ISSUE(eB, kB, vB, i + 3);
        }
        if (i + 2 < end) {          // 3 edges left: A(i), B(i+1), then A(i+2)
            COMPUTE(eA, kA, vA); ISSUE(eA, kA, vA, i + 2);
            COMPUTE(eB, kB, vB);
            COMPUTE(eA, kA, vA);
        } else {                    // 2 edges left
            COMPUTE(eA, kA, vA);
            COMPUTE(eB, kB, vB);
        }
    } else if (n == 1) {
        ISSUE(eA, kA, vA, beg);
        COMPUTE(eA, kA, vA);
    }
#undef ISSUE
#undef COMPUTE

    const float inv = 1.0f / (den + 1e-16f);
    const size_t ob = (size_t)node * 256 + c0;
    f32x4 o = *(f32x4*)(out + ob);       // skip from gemm_qkvs outSel==3
    o[0] += va[0] * inv; o[1] += va[1] * inv; o[2] += va[2] * inv; o[3] += va[3] * inv;
    *(f32x4*)(out + ob) = o;
#pragma unroll
    for (int m = 0; m < 8; ++m) {
        f16x4 zh;
        zh[0] = (f16)(z[m][0] * inv); zh[1] = (f16)(z[m][1] * inv);
        zh[2] = (f16)(z[m][2] * inv); zh[3] = (f16)(z[m][3] * inv);
        *(f16x4*)(G + (size_t)node * 2048 + h * 256 + m * 32 + j * 4) = zh;
    }
}

// ---- Z GEMM (per-head): out[i, h*32+c] += sum_d zhat[i,h,d] * We[d, h*32+c] ----
__global__ __launch_bounds__(512, 4) void gemm_z2(
    const f16* __restrict__ zf, const f16* __restrict__ WTe, float* __restrict__ out)
{
    const int tid = threadIdx.x;
    const int wave = tid >> 6, lane = tid & 63;
    const int l16 = lane & 15, lg = lane >> 4;
    const int h = blockIdx.y;
    const int rowBase = blockIdx.x * 128 + wave * 16;

    int arow = rowBase + l16;
    if (arow >= N_NODES) arow = N_NODES - 1;
    const f16* ap = zf + (size_t)arow * 2048 + h * 256 + lg * 8;

    f32x4 acc[2];
    acc[0] = (f32x4){0.f, 0.f, 0.f, 0.f};
    acc[1] = (f32x4){0.f, 0.f, 0.f, 0.f};
#pragma unroll
    for (int ks = 0; ks < 8; ++ks) {
        f16x8 a = *(const f16x8*)(ap + ks * 32);
#pragma unroll
        for (int ct = 0; ct < 2; ++ct) {
            f16x8 b = *(const f16x8*)(WTe + (size_t)(h * 32 + ct * 16 + l16) * 256 + ks * 32 + lg * 8);
            acc[ct] = __builtin_amdgcn_mfma_f32_16x16x32_f16(a, b, acc[ct], 0, 0, 0);
        }
    }
#pragma unroll
    for (int ct = 0; ct < 2; ++ct) {
        const int col = h * 32 + ct * 16 + l16;
#pragma unroll
        for (int i = 0; i < 4; ++i) {
            const int row = rowBase + lg * 4 + i;
            if (row < N_NODES)
                out[(size_t)row * 256 + col] += acc[ct][i];
        }
    }
}

extern "C" void kernel_launch(void* const* d_in, const int* in_sizes, int n_in,
                              void* d_out, int out_size, void* d_ws, size_t ws_size,
                              hipStream_t stream) {
    const float* x   = (const float*)d_in[0];
    const int*   ei  = (const int*)d_in[1];     // [0..E): src, [E..2E): dst
    const float* ea  = (const float*)d_in[2];
    const float* Wq  = (const float*)d_in[3];
    const float* bq  = (const float*)d_in[4];
    const float* Wk  = (const float*)d_in[5];
    const float* bk  = (const float*)d_in[6];
    const float* Wv  = (const float*)d_in[7];
    const float* bv  = (const float*)d_in[8];
    const float* We  = (const float*)d_in[9];
    const float* Ws  = (const float*)d_in[10];
    const float* bs  = (const float*)d_in[11];
    float* out = (float*)d_out;

    const int* srcArr = ei;
    const int* dstArr = ei + N_EDGES;

    // workspace layout (~116 MB)
    char* w = (char*)d_ws;
    size_t off = 0;
    f16* wtbase = (f16*)(w + off); off += 5 * 65536 * 2;            // q,k,v,s,e transposed
    f16* wef16  = (f16*)(w + off); off += 65536 * 2;                // We row-major f16
    f16* qf = (f16*)(w + off); off += (size_t)N_NODES * 256 * 2;
    f16* kf = (f16*)(w + off); off += (size_t)N_NODES * 256 * 2;
    f16* vf = (f16*)(w + off); off += (size_t)N_NODES * 256 * 2;
    f16* G  = (f16*)(w + off); off += (size_t)N_NODES * 2048 * 2;   // G, then zhat (reused)
    int* deg    = (int*)(w + off); off += 80016;
    int* rowptr = (int*)(w + off); off += 80016;
    int* cursor = (int*)(w + off); off += 80016;
    int2* es    = (int2*)(w + off); off += (size_t)N_EDGES * 8;     // (eid, src) per CSR slot
    float* biasAll = (float*)(w + off); off += 4 * 256 * 4;
    (void)ws_size; (void)n_in; (void)in_sizes; (void)out_size;

    // prep: weight transposes + We f16 + bias pack + deg zero
    prep_all<<<1540 + (N_NODES + 255) / 256, 256, 0, stream>>>(
        Wq, Wk, Wv, Ws, We, bq, bk, bv, bs, wtbase, wef16, biasAll, deg);

    // CSR build
    count_deg<<<(N_EDGES + 255) / 256, 256, 0, stream>>>(dstArr, deg);
    scan_deg<<<1, 1024, 0, stream>>>(deg, rowptr, cursor);
    scatter_edges<<<(N_EDGES + 255) / 256, 256, 0, stream>>>(srcArr, dstArr, cursor, es);

    // node GEMMs: q,k,v,skip
    dim3 gnode((N_NODES + 127) / 128, 8);
    gemm_qkvs<<<gnode, 512, 0, stream>>>(x, wtbase, biasAll, qf, out);

    // G = per-(node,head) 256-d logit vectors
    dim3 gg((N_NODES + 63) / 64, 8);
    gemm_g<<<gg, 256, 0, stream>>>(qf, wef16, G);

    // fused attention aggregate (streams ea once; overwrites G with zhat)
    aggregate4<<<(N_NODES + 3) / 4, 256, 0, stream>>>(
        qf, kf, vf, G, ea, es, rowptr, out);

    // out += zhat_h @ We (per head)
    dim3 gz((N_NODES + 127) / 128, 8);
    gemm_z2<<<gz, 512, 0, stream>>>(G, wtbase + 4 * 65536, out);
}

// Round 11
// 450.492 us; speedup vs baseline: 1.5446x; 1.5446x over previous
//
#include <hip/hip_runtime.h>
#include <hip/hip_fp16.h>

#define N_NODES 20000
#define N_EDGES 320000
#define DIM 256
// H=8 heads, C=32 channels/head

typedef _Float16 f16;
typedef unsigned int u32;
typedef f16 f16x8 __attribute__((ext_vector_type(8)));
typedef f16 f16x4 __attribute__((ext_vector_type(4)));
typedef float f32x4 __attribute__((ext_vector_type(4)));

#define GLL16(gsrc, ldst) __builtin_amdgcn_global_load_lds( \
    (const u32 __attribute__((address_space(1)))*)(gsrc),   \
    (u32 __attribute__((address_space(3)))*)(ldst), 16, 0, 0)

// ---- prep: weights f32 (K x N) -> f16 transposed (N x K); We f16 row-major;
//      pack biases; zero deg ----
__global__ void prep_all(const float* __restrict__ Wq, const float* __restrict__ Wk,
                         const float* __restrict__ Wv, const float* __restrict__ Ws,
                         const float* __restrict__ We,
                         const float* __restrict__ bq, const float* __restrict__ bk,
                         const float* __restrict__ bv, const float* __restrict__ bs,
                         f16* __restrict__ wtbase, f16* __restrict__ wef16,
                         float* __restrict__ biasAll, int* __restrict__ deg) {
    if (blockIdx.x < 1280) {
        int gid = blockIdx.x * 256 + threadIdx.x;
        int w = gid >> 16;            // 0..4 : q,k,v,s,e
        int idx = gid & 65535;
        int k = idx >> 8, n = idx & 255;
        const float* W = (w == 0) ? Wq : (w == 1) ? Wk : (w == 2) ? Wv : (w == 3) ? Ws : We;
        wtbase[w * 65536 + n * 256 + k] = (f16)W[k * 256 + n];
    } else if (blockIdx.x < 1536) {
        int idx = (blockIdx.x - 1280) * 256 + threadIdx.x;  // 0..65535
        wef16[idx] = (f16)We[idx];                          // row-major [d][hc]
    } else if (blockIdx.x < 1540) {
        int i = (blockIdx.x - 1536) * 256 + threadIdx.x;    // 0..1023
        int y = i >> 8, col = i & 255;
        const float* b = (y == 0) ? bq : (y == 1) ? bk : (y == 2) ? bv : bs;
        biasAll[i] = b[col];
    } else {
        int i = (blockIdx.x - 1540) * 256 + threadIdx.x;
        if (i < N_NODES) deg[i] = 0;
    }
}

// ---- node GEMM (R4-proven): q,k,v (f16) + skip (f32), grid (157, 8) ----
__global__ __launch_bounds__(512, 4) void gemm_qkvs(
    const float* __restrict__ A, const f16* __restrict__ WTbase,
    const float* __restrict__ biasAll,
    f16* __restrict__ outF16, float* __restrict__ outF32)
{
    __shared__ __align__(16) char lds[65536];
    const int tid = threadIdx.x;
    const int wave = tid >> 6, lane = tid & 63;
    const int l16 = lane & 15, lg = lane >> 4;
    const int y = blockIdx.y;
    const int outSel = y >> 1, colHalf = y & 1;
    const f16* __restrict__ WT = WTbase + outSel * 65536 + colHalf * 128 * 256;
    const int rowBase = blockIdx.x * 128 + wave * 16;

    const int slot = rowBase + l16;
    const int arow = (slot < N_NODES) ? slot : N_NODES - 1;
    const float* ap = A + (size_t)arow * DIM;
    f32x4 lo[8], hi[8];
#pragma unroll
    for (int ks = 0; ks < 8; ++ks) {
        lo[ks] = *(const f32x4*)(ap + ks * 32 + lg * 8);
        hi[ks] = *(const f32x4*)(ap + ks * 32 + lg * 8 + 4);
    }
    {
        const int p = lane & 31;
#pragma unroll
        for (int r = 0; r < 8; ++r) {
            const int nrel = wave * 16 + r * 2 + (lane >> 5);
            const f16* src = WT + nrel * 256 + (p ^ (nrel & 31)) * 8;
            GLL16(src, &lds[(wave * 16 + r * 2) * 512]);
        }
    }
    f16x8 afr[8];
#pragma unroll
    for (int ks = 0; ks < 8; ++ks) {
#pragma unroll
        for (int j = 0; j < 4; ++j) {
            afr[ks][j]     = (f16)lo[ks][j];
            afr[ks][4 + j] = (f16)hi[ks][j];
        }
    }
    f32x4 acc[8];
#pragma unroll
    for (int c = 0; c < 8; ++c) acc[c] = (f32x4){0.f, 0.f, 0.f, 0.f};

    __syncthreads();

#pragma unroll
    for (int ks = 0; ks < 8; ++ks) {
#pragma unroll
        for (int ct = 0; ct < 8; ++ct) {
            const int nrel = ct * 16 + l16;
            f16x8 b = *(const f16x8*)(lds + nrel * 512 + (((ks * 4 + lg) ^ (nrel & 31)) * 16));
            acc[ct] = __builtin_amdgcn_mfma_f32_16x16x32_f16(afr[ks], b, acc[ct], 0, 0, 0);
        }
    }
#pragma unroll
    for (int ct = 0; ct < 8; ++ct) {
        const int col = colHalf * 128 + ct * 16 + l16;
        const float bv = biasAll[outSel * 256 + col];
#pragma unroll
        for (int i = 0; i < 4; ++i) {
            const int row = rowBase + lg * 4 + i;
            if (row < N_NODES) {
                const float val = acc[ct][i] + bv;
                if (outSel < 3)
                    (outF16 + (size_t)outSel * N_NODES * 256)[(size_t)row * 256 + col] = (f16)val;
                else
                    outF32[(size_t)row * 256 + col] = val;
            }
        }
    }
}

// ---- G GEMM: G[i,h,d] = sum_c We[d, h*32+c] * q[i, h*32+c]  (f16 out) ----
__global__ __launch_bounds__(256, 4) void gemm_g(
    const f16* __restrict__ qf, const f16* __restrict__ wef16, f16* __restrict__ G)
{
    const int tid = threadIdx.x;
    const int wave = tid >> 6, lane = tid & 63;
    const int l16 = lane & 15, lg = lane >> 4;
    const int h = blockIdx.y;
    const int rowBase = blockIdx.x * 64 + wave * 16;

    int arow = rowBase + l16;
    if (arow >= N_NODES) arow = N_NODES - 1;
    f16x8 a = *(const f16x8*)(qf + (size_t)arow * 256 + h * 32 + lg * 8);

    f32x4 acc[16];
#pragma unroll
    for (int c = 0; c < 16; ++c) acc[c] = (f32x4){0.f, 0.f, 0.f, 0.f};
#pragma unroll
    for (int ct = 0; ct < 16; ++ct) {
        f16x8 b = *(const f16x8*)(wef16 + (size_t)(ct * 16 + l16) * 256 + h * 32 + lg * 8);
        acc[ct] = __builtin_amdgcn_mfma_f32_16x16x32_f16(a, b, acc[ct], 0, 0, 0);
    }
#pragma unroll
    for (int ct = 0; ct < 16; ++ct) {
        const int d = ct * 16 + l16;
#pragma unroll
        for (int i = 0; i < 4; ++i) {
            const int row = rowBase + lg * 4 + i;
            if (row < N_NODES)
                G[(size_t)row * 2048 + h * 256 + d] = (f16)acc[ct][i];
        }
    }
}

// ---- CSR build (by dst) ----
__global__ void count_deg(const int* __restrict__ dst, int* __restrict__ deg) {
    int e = blockIdx.x * blockDim.x + threadIdx.x;
    if (e < N_EDGES) atomicAdd(&deg[dst[e]], 1);
}

__global__ __launch_bounds__(1024) void scan_deg(const int* __restrict__ deg,
                                                 int* __restrict__ rowptr,
                                                 int* __restrict__ cursor) {
    __shared__ int part[1024];
    const int t = threadIdx.x;
    const int CH = (N_NODES + 1023) / 1024; // 20
    const int base = t * CH;
    int s = 0;
    for (int i = 0; i < CH; ++i) { int n = base + i; if (n < N_NODES) s += deg[n]; }
    part[t] = s;
    __syncthreads();
    for (int off = 1; off < 1024; off <<= 1) {
        int v = (t >= off) ? part[t - off] : 0;
        __syncthreads();
        part[t] += v;
        __syncthreads();
    }
    int run = (t == 0) ? 0 : part[t - 1];
    for (int i = 0; i < CH; ++i) {
        int n = base + i;
        if (n < N_NODES) { int dn = deg[n]; rowptr[n] = run; cursor[n] = run; run += dn; }
    }
    if (t == 1023) rowptr[N_NODES] = part[1023]; // == E
}

__global__ void scatter_edges(const int* __restrict__ src, const int* __restrict__ dst,
                              int* __restrict__ cursor, int2* __restrict__ es) {
    int e = blockIdx.x * blockDim.x + threadIdx.x;
    if (e < N_EDGES) {
        int p = atomicAdd(&cursor[dst[e]], 1);
        es[p] = make_int2(e, src[e]);   // CSR slot -> (edge id, source node)
    }
}

// ---- fused attention aggregate v5: TWO waves per node (edge-strided halves) ----
// Block 256 thr = 4 waves = 2 nodes x 2 waves; grid = N/2 (exact).
// Each wave runs the proven R9 body (no per-wave pipelining -> no spills) over
// slots {beg+sub, +2, ...}; partial (z[8], va, den) combined via LDS (stride-37
// float rows -> conflict-free). Doubles waves-in-flight on the latency-bound
// gather -> ~2x. lane l: head h=l>>3, sublane j=l&7; c0=l*4.
// End (waves with sub==0): out += va/den; G[node][h][:] = zhat = z/den (f16).
__global__ __launch_bounds__(256) void aggregate5(
    const f16* __restrict__ qf, const f16* __restrict__ kf, const f16* __restrict__ vf,
    f16* __restrict__ G, const float* __restrict__ ea,
    const int2* __restrict__ es, const int* __restrict__ rowptr,
    float* __restrict__ out)
{
    __shared__ float red[4][64][37];
    const int wave = threadIdx.x >> 6;
    const int lane = threadIdx.x & 63;
    const int sub  = wave & 1;
    const int node = blockIdx.x * 2 + (wave >> 1);
    const int h = lane >> 3, j = lane & 7;
    const int c0 = lane * 4;

    f32x4 qv;
    {
        f16x4 qh = *(const f16x4*)(qf + (size_t)node * 256 + c0);
        qv = (f32x4){(float)qh[0], (float)qh[1], (float)qh[2], (float)qh[3]};
    }
    f32x4 ga[8];
#pragma unroll
    for (int m = 0; m < 8; ++m) {
        f16x4 gh = *(const f16x4*)(G + (size_t)node * 2048 + h * 256 + m * 32 + j * 4);
        ga[m] = (f32x4){(float)gh[0], (float)gh[1], (float)gh[2], (float)gh[3]};
    }

    f32x4 z[8];
#pragma unroll
    for (int m = 0; m < 8; ++m) z[m] = (f32x4){0.f, 0.f, 0.f, 0.f};
    f32x4 va = (f32x4){0.f, 0.f, 0.f, 0.f};
    float den = 0.f;
    const int beg = rowptr[node], end = rowptr[node + 1];

    int idx = beg + sub;
    int2 cur;
    if (idx < end) cur = es[idx];
    for (; idx < end; idx += 2) {
        const int2 nxt = (idx + 2 < end) ? es[idx + 2] : make_int2(0, 0);
        const float* ep = ea + (size_t)cur.x * 256 + j * 4;
        f32x4 e0 = *(const f32x4*)(ep + 0 * 32);
        f32x4 e1 = *(const f32x4*)(ep + 1 * 32);
        f32x4 e2 = *(const f32x4*)(ep + 2 * 32);
        f32x4 e3 = *(const f32x4*)(ep + 3 * 32);
        f32x4 e4 = *(const f32x4*)(ep + 4 * 32);
        f32x4 e5 = *(const f32x4*)(ep + 5 * 32);
        f32x4 e6 = *(const f32x4*)(ep + 6 * 32);
        f32x4 e7 = *(const f32x4*)(ep + 7 * 32);
        f16x4 kh = *(const f16x4*)(kf + (size_t)cur.y * 256 + c0);
        f16x4 vh = *(const f16x4*)(vf + (size_t)cur.y * 256 + c0);

        float dm0 = e0[0]*ga[0][0] + e0[1]*ga[0][1] + e0[2]*ga[0][2] + e0[3]*ga[0][3];
        float dm1 = e1[0]*ga[1][0] + e1[1]*ga[1][1] + e1[2]*ga[1][2] + e1[3]*ga[1][3];
        float dm2 = e2[0]*ga[2][0] + e2[1]*ga[2][1] + e2[2]*ga[2][2] + e2[3]*ga[2][3];
        float dm3 = e3[0]*ga[3][0] + e3[1]*ga[3][1] + e3[2]*ga[3][2] + e3[3]*ga[3][3];
        float dm4 = e4[0]*ga[4][0] + e4[1]*ga[4][1] + e4[2]*ga[4][2] + e4[3]*ga[4][3];
        float dm5 = e5[0]*ga[5][0] + e5[1]*ga[5][1] + e5[2]*ga[5][2] + e5[3]*ga[5][3];
        float dm6 = e6[0]*ga[6][0] + e6[1]*ga[6][1] + e6[2]*ga[6][2] + e6[3]*ga[6][3];
        float dm7 = e7[0]*ga[7][0] + e7[1]*ga[7][1] + e7[2]*ga[7][2] + e7[3]*ga[7][3];
        float p = ((dm0 + dm1) + (dm2 + dm3)) + ((dm4 + dm5) + (dm6 + dm7));
        p += qv[0]*(float)kh[0] + qv[1]*(float)kh[1] + qv[2]*(float)kh[2] + qv[3]*(float)kh[3];
        p += __shfl_xor(p, 1);
        p += __shfl_xor(p, 2);
        p += __shfl_xor(p, 4);
        const float al = __expf(p * 0.1767766952966369f);  // 1/sqrt(32)
        den += al;
        va[0] += al * (float)vh[0]; va[1] += al * (float)vh[1];
        va[2] += al * (float)vh[2]; va[3] += al * (float)vh[3];
        z[0][0] += al*e0[0]; z[0][1] += al*e0[1]; z[0][2] += al*e0[2]; z[0][3] += al*e0[3];
        z[1][0] += al*e1[0]; z[1][1] += al*e1[1]; z[1][2] += al*e1[2]; z[1][3] += al*e1[3];
        z[2][0] += al*e2[0]; z[2][1] += al*e2[1]; z[2][2] += al*e2[2]; z[2][3] += al*e2[3];
        z[3][0] += al*e3[0]; z[3][1] += al*e3[1]; z[3][2] += al*e3[2]; z[3][3] += al*e3[3];
        z[4][0] += al*e4[0]; z[4][1] += al*e4[1]; z[4][2] += al*e4[2]; z[4][3] += al*e4[3];
        z[5][0] += al*e5[0]; z[5][1] += al*e5[1]; z[5][2] += al*e5[2]; z[5][3] += al*e5[3];
        z[6][0] += al*e6[0]; z[6][1] += al*e6[1]; z[6][2] += al*e6[2]; z[6][3] += al*e6[3];
        z[7][0] += al*e7[0]; z[7][1] += al*e7[1]; z[7][2] += al*e7[2]; z[7][3] += al*e7[3];
        cur = nxt;
    }

    // ---- combine the two halves via LDS ----
    {
        float* rp = &red[wave][lane][0];
#pragma unroll
        for (int m = 0; m < 8; ++m) {
            rp[m * 4 + 0] = z[m][0]; rp[m * 4 + 1] = z[m][1];
            rp[m * 4 + 2] = z[m][2]; rp[m * 4 + 3] = z[m][3];
        }
        rp[32] = va[0]; rp[33] = va[1]; rp[34] = va[2]; rp[35] = va[3];
        rp[36] = den;
    }
    __syncthreads();
    if (sub == 0) {
        const float* ra = &red[wave][lane][0];
        const float* rb = &red[wave + 1][lane][0];
        const float dsum = ra[36] + rb[36];
        const float inv = 1.0f / (dsum + 1e-16f);
        const size_t ob = (size_t)node * 256 + c0;
        f32x4 o = *(f32x4*)(out + ob);       // skip from gemm_qkvs outSel==3
        o[0] += (ra[32] + rb[32]) * inv; o[1] += (ra[33] + rb[33]) * inv;
        o[2] += (ra[34] + rb[34]) * inv; o[3] += (ra[35] + rb[35]) * inv;
        *(f32x4*)(out + ob) = o;
#pragma unroll
        for (int m = 0; m < 8; ++m) {
            f16x4 zh;
            zh[0] = (f16)((ra[m * 4 + 0] + rb[m * 4 + 0]) * inv);
            zh[1] = (f16)((ra[m * 4 + 1] + rb[m * 4 + 1]) * inv);
            zh[2] = (f16)((ra[m * 4 + 2] + rb[m * 4 + 2]) * inv);
            zh[3] = (f16)((ra[m * 4 + 3] + rb[m * 4 + 3]) * inv);
            *(f16x4*)(G + (size_t)node * 2048 + h * 256 + m * 32 + j * 4) = zh;
        }
    }
}

// ---- Z GEMM (per-head): out[i, h*32+c] += sum_d zhat[i,h,d] * We[d, h*32+c] ----
__global__ __launch_bounds__(512, 4) void gemm_z2(
    const f16* __restrict__ zf, const f16* __restrict__ WTe, float* __restrict__ out)
{
    const int tid = threadIdx.x;
    const int wave = tid >> 6, lane = tid & 63;
    const int l16 = lane & 15, lg = lane >> 4;
    const int h = blockIdx.y;
    const int rowBase = blockIdx.x * 128 + wave * 16;

    int arow = rowBase + l16;
    if (arow >= N_NODES) arow = N_NODES - 1;
    const f16* ap = zf + (size_t)arow * 2048 + h * 256 + lg * 8;

    f32x4 acc[2];
    acc[0] = (f32x4){0.f, 0.f, 0.f, 0.f};
    acc[1] = (f32x4){0.f, 0.f, 0.f, 0.f};
#pragma unroll
    for (int ks = 0; ks < 8; ++ks) {
        f16x8 a = *(const f16x8*)(ap + ks * 32);
#pragma unroll
        for (int ct = 0; ct < 2; ++ct) {
            f16x8 b = *(const f16x8*)(WTe + (size_t)(h * 32 + ct * 16 + l16) * 256 + ks * 32 + lg * 8);
            acc[ct] = __builtin_amdgcn_mfma_f32_16x16x32_f16(a, b, acc[ct], 0, 0, 0);
        }
    }
#pragma unroll
    for (int ct = 0; ct < 2; ++ct) {
        const int col = h * 32 + ct * 16 + l16;
#pragma unroll
        for (int i = 0; i < 4; ++i) {
            const int row = rowBase + lg * 4 + i;
            if (row < N_NODES)
                out[(size_t)row * 256 + col] += acc[ct][i];
        }
    }
}

extern "C" void kernel_launch(void* const* d_in, const int* in_sizes, int n_in,
                              void* d_out, int out_size, void* d_ws, size_t ws_size,
                              hipStream_t stream) {
    const float* x   = (const float*)d_in[0];
    const int*   ei  = (const int*)d_in[1];     // [0..E): src, [E..2E): dst
    const float* ea  = (const float*)d_in[2];
    const float* Wq  = (const float*)d_in[3];
    const float* bq  = (const float*)d_in[4];
    const float* Wk  = (const float*)d_in[5];
    const float* bk  = (const float*)d_in[6];
    const float* Wv  = (const float*)d_in[7];
    const float* bv  = (const float*)d_in[8];
    const float* We  = (const float*)d_in[9];
    const float* Ws  = (const float*)d_in[10];
    const float* bs  = (const float*)d_in[11];
    float* out = (float*)d_out;

    const int* srcArr = ei;
    const int* dstArr = ei + N_EDGES;

    // workspace layout (~116 MB)
    char* w = (char*)d_ws;
    size_t off = 0;
    f16* wtbase = (f16*)(w + off); off += 5 * 65536 * 2;            // q,k,v,s,e transposed
    f16* wef16  = (f16*)(w + off); off += 65536 * 2;                // We row-major f16
    f16* qf = (f16*)(w + off); off += (size_t)N_NODES * 256 * 2;
    f16* kf = (f16*)(w + off); off += (size_t)N_NODES * 256 * 2;
    f16* vf = (f16*)(w + off); off += (size_t)N_NODES * 256 * 2;
    f16* G  = (f16*)(w + off); off += (size_t)N_NODES * 2048 * 2;   // G, then zhat (reused)
    int* deg    = (int*)(w + off); off += 80016;
    int* rowptr = (int*)(w + off); off += 80016;
    int* cursor = (int*)(w + off); off += 80016;
    int2* es    = (int2*)(w + off); off += (size_t)N_EDGES * 8;     // (eid, src) per CSR slot
    float* biasAll = (float*)(w + off); off += 4 * 256 * 4;
    (void)ws_size; (void)n_in; (void)in_sizes; (void)out_size;

    // prep: weight transposes + We f16 + bias pack + deg zero
    prep_all<<<1540 + (N_NODES + 255) / 256, 256, 0, stream>>>(
        Wq, Wk, Wv, Ws, We, bq, bk, bv, bs, wtbase, wef16, biasAll, deg);

    // CSR build
    count_deg<<<(N_EDGES + 255) / 256, 256, 0, stream>>>(dstArr, deg);
    scan_deg<<<1, 1024, 0, stream>>>(deg, rowptr, cursor);
    scatter_edges<<<(N_EDGES + 255) / 256, 256, 0, stream>>>(srcArr, dstArr, cursor, es);

    // node GEMMs: q,k,v,skip
    dim3 gnode((N_NODES + 127) / 128, 8);
    gemm_qkvs<<<gnode, 512, 0, stream>>>(x, wtbase, biasAll, qf, out);

    // G = per-(node,head) 256-d logit vectors
    dim3 gg((N_NODES + 63) / 64, 8);
    gemm_g<<<gg, 256, 0, stream>>>(qf, wef16, G);

    // fused attention aggregate (2 waves/node; streams ea once; G -> zhat)
    aggregate5<<<N_NODES / 2, 256, 0, stream>>>(
        qf, kf, vf, G, ea, es, rowptr, out);

    // out += zhat_h @ We (per head)
    dim3 gz((N_NODES + 127) / 128, 8);
    gemm_z2<<<gz, 512, 0, stream>>>(G, wtbase + 4 * 65536, out);
}